// Round 9
// baseline (586.389 us; speedup 1.0000x reference)
//
#include <hip/hip_runtime.h>

// MaxUnpooling2D scatter-add — FULL-PLANE 2-channel privatization, single
// generation. updates/mask: [32,64,64,128] f32/i32, out: [32,128,128,128].
// out flat = (b<<21) | (bin<<7) | c, bin = mask>>7 in [0,16384).
//
// R3..R10 ledger: time pinned at 180-190us while granularity (16->64B),
// occupancy (8->32 waves/CU), HBM bytes (431->336MB), pass count (4 vs 16),
// and barrier-drain semantics ALL proved null. Only spill rounds moved time
// — in proportion to L3-side bytes. Conclusion: the invariant is the
// phase-serialized L-then-S schedule every variant shared (register-cache
// whole input, then barrier-locked passes; all blocks phase-locked, so
// machine-wide reads never overlap machine-wide writes).
//
// R11 (re-run; R8 bench was a container-acquisition infra failure, kernel
// never executed): restructure. Block = (batch, 2 channels); LDS
// [16384 bins][2ch] = 128 KiB = the WHOLE output plane -> ONE generation:
//   stream loads -> immediate ds_add (no register cache, no scans, no
//   passes) -> one barrier -> one contiguous store sweep.
// 2048 blocks / 8 residency rounds: round r+1's loads overlap round r's
// fire-and-forget store drain -> load/store finally pipeline machine-wide.
//
// XCD-sector alignment: x=bid&7 (XCD), r=bid>>3, g=x*8+(r&7), b=r>>3.
//  * XCD x owns channels 16x..16x+15 (sector x of every 512B line):
//    - input: its L2 fetches exactly 1/8 of each line, zero over-fetch;
//    - output: 64B sector x is assembled in L2 from 8 same-XCD co-resident
//      partners; L3 merges the 8 sectors per line across XCDs.
//  * all 64 partners of a line are co-resident in the same round
//    (round = 4 consecutive batches x all 64 groups).
// Store granule 8B/bin — granularity is a proven-null axis (R5/R9/R10).

#define HWC   (64 * 64 * 128)   // 2^19 input elements per batch
#define NBINS 16384

__global__ __launch_bounds__(1024) void unpool_fp2(
    const float* __restrict__ upd, const int* __restrict__ mask,
    float* __restrict__ out)
{
    extern __shared__ float acc[];     // [16384 bins][2 ch] = 128 KiB

    int bid = blockIdx.x;
    int x   = bid & 7;                 // XCD / channel-sector
    int r   = bid >> 3;                // 0..255
    int g   = x * 8 + (r & 7);         // channel group 0..63
    int b   = r >> 3;                  // batch 0..31
    int c0  = g << 1;                  // channel base, 0..126

    int t = threadIdx.x;

    const float* ubase = upd  + (size_t)b * HWC + c0;
    const int*   mbase = mask + (size_t)b * HWC + c0;
    float*       obase = out + ((size_t)b << 21) + c0;

    // zero the full plane: 8 float4 per thread (128 KiB)
    float4* a4 = (float4*)acc;
    #pragma unroll
    for (int k = 0; k < 8; ++k)
        a4[t + k * 1024] = make_float4(0.f, 0.f, 0.f, 0.f);
    __syncthreads();

    // stream: load 4 positions per thread, scatter immediately.
    // Each element touched exactly once — no scans, no predication.
    #pragma unroll
    for (int k = 0; k < 4; ++k) {
        int pos = t + (k << 10);       // (h,w) position 0..4095
        float2 u2 = *(const float2*)(ubase + (size_t)pos * 128);
        int2   m2 = *(const int2*)  (mbase + (size_t)pos * 128);
        unsigned b0 = ((unsigned)m2.x) >> 7;   // bin for channel c0
        unsigned b1 = ((unsigned)m2.y) >> 7;   // bin for channel c0+1
        atomicAdd(&acc[(b0 << 1) + 0], u2.x);
        atomicAdd(&acc[(b1 << 1) + 1], u2.y);
    }
    __syncthreads();

    // store sweep: 16 bins per thread, 8B (float2) per bin.
    // Consecutive lanes -> consecutive bins (512B-strided lines); the 8
    // same-XCD partners fill sector x; L2/L3 merge to full lines.
    #pragma unroll
    for (int k = 0; k < 16; ++k) {
        int bin = t + (k << 10);
        float2 v = *(const float2*)(acc + (bin << 1));
        *(float2*)(obase + (size_t)bin * 128) = v;
    }
}

extern "C" void kernel_launch(void* const* d_in, const int* in_sizes, int n_in,
                              void* d_out, int out_size, void* d_ws, size_t ws_size,
                              hipStream_t stream) {
    const float* upd  = (const float*)d_in[0];
    const int*   mask = (const int*)d_in[1];
    float*       out  = (float*)d_out;

    // 128 KiB dynamic LDS opt-in (host-side, idempotent, not a stream op ->
    // graph-capture safe; unguarded so a fresh context always gets it).
    hipFuncSetAttribute((const void*)unpool_fp2,
                        hipFuncAttributeMaxDynamicSharedMemorySize,
                        NBINS * 2 * 4);

    // 32 batches x 64 two-channel groups; every output element written
    // exactly once -> no memset, no global atomics.
    unpool_fp2<<<2048, 1024, NBINS * 2 * 4, stream>>>(upd, mask, out);
}